// Round 22
// baseline (109.709 us; speedup 1.0000x reference)
//
#include <hip/hip_runtime.h>

#define S_LEN 2048
#define DM 1024
#define NH 16
#define HD 64
#define NB 2

typedef unsigned short u16;
typedef __attribute__((ext_vector_type(8))) short s16x8;
typedef __attribute__((ext_vector_type(8))) unsigned short u16x8;
typedef __attribute__((ext_vector_type(4))) float fx4;
typedef __attribute__((ext_vector_type(2))) unsigned u32x2;
typedef __attribute__((ext_vector_type(4))) unsigned u32x4;

__device__ __forceinline__ u16 f2bf(float f) {
  unsigned u = __builtin_bit_cast(unsigned, f);
  return (u16)((u + 0x7FFFu + ((u >> 16) & 1u)) >> 16);
}

// packed fp32x2 -> bf16x2 (low = a, high = b); no builtin on gfx950 (T12 recipe)
__device__ __forceinline__ unsigned cvt_pk_bf16(float a, float b) {
  unsigned r;
  asm("v_cvt_pk_bf16_f32 %0, %1, %2" : "=v"(r) : "v"(a), "v"(b));
  return r;
}

__device__ __forceinline__ void gload16(const void* g, void* l) {
  __builtin_amdgcn_global_load_lds(
      (const __attribute__((address_space(1))) unsigned*)g,
      (__attribute__((address_space(3))) unsigned*)l, 16, 0, 0);
}

__device__ __forceinline__ fx4 mfma16(s16x8 a, s16x8 b, fx4 c) {
  return __builtin_amdgcn_mfma_f32_16x16x32_bf16(a, b, c, 0, 0, 0);
}

// ---------------- fp32 -> bf16 convert: WEIGHTS ONLY ----------------
// Wq gets 0.125 (1/sqrt(hd)) * 1.44269504 (log2 e): scores land in log2 domain.
__global__ __launch_bounds__(256) void cvt_w_kernel(
    const float* __restrict__ Wq, const float* __restrict__ Wk,
    const float* __restrict__ Wv, const float* __restrict__ Wo,
    u16* __restrict__ Wqb, u16* __restrict__ Wkb, u16* __restrict__ Wvb,
    u16* __restrict__ Wob) {
  const int blk = blockIdx.x;
  const float* src;
  u16* dst;
  float scale = 1.0f;
  int off;
  if (blk < 512)       { src = Wq; dst = Wqb; off = blk;        scale = 0.18033688f; }
  else if (blk < 1024) { src = Wk; dst = Wkb; off = blk - 512;  }
  else if (blk < 1536) { src = Wv; dst = Wvb; off = blk - 1024; }
  else                 { src = Wo; dst = Wob; off = blk - 1536; }
  const int i = (off * 256 + (int)threadIdx.x) * 8;
  fx4 a = *(const fx4*)(src + i);
  fx4 b = *(const fx4*)(src + i + 4);
  u16x8 o;
  o[0] = f2bf(a[0] * scale); o[1] = f2bf(a[1] * scale);
  o[2] = f2bf(a[2] * scale); o[3] = f2bf(a[3] * scale);
  o[4] = f2bf(b[0] * scale); o[5] = f2bf(b[1] * scale);
  o[6] = f2bf(b[2] * scale); o[7] = f2bf(b[3] * scale);
  *(u16x8*)(dst + i) = o;
}

__device__ __forceinline__ void store_out(u16* C, size_t idx, float v) { C[idx] = f2bf(v); }
__device__ __forceinline__ void store_out(float* C, size_t idx, float v) { C[idx] = v; }

// ---------------- qkv GEMM: fp32 A, 2-buffer counted-vmcnt pipeline ----------------
// A stored as HALF-ROW LDS layout to kill the 128B-stride bank aliasing (R21's
// 3.1M conflicts): fp32 row r -> two 64B LDS rows (2r+h), h = src_chunk>>2;
// slot = (c&3)^(r&3). Bank = h*16 + slot*4 + w: depends on row AND chunk -> <=2-way
// (free). Store stays a LINEAR gload dest; the permutation lives in the per-lane
// SOURCE address (rule 21). Frags: x at (2r+(g>>1))*64+(((2g)&3)^(r&3))*16, y=x^16.
__device__ __forceinline__ void gemm_f32_pipe(const float* __restrict__ Afp,
                                              const u16* __restrict__ Bt,
                                              const float* __restrict__ bias,
                                              float bscale, u16* __restrict__ C,
                                              u16* __restrict__ vt, bool vout,
                                              int m0, int n0) {
  __shared__ u16 Al[2][128 * 64];  // fp32 tile as 256 x 64B half-rows: 16 KB each
  __shared__ u16 Bl[2][128 * 32];  // 8 KB each
  const int tid = threadIdx.x;
  const int wid = tid >> 6, lane = tid & 63;
  const int g = lane >> 4, lr = lane & 15;
  const int wr = wid >> 1, wc = wid & 1;
  const int row0 = tid >> 2, ch = tid & 3;  // B: 128 rows x 4 chunks(16B)
  const int chx = ch ^ ((row0 >> 1) & 3);   // B pre-swizzled source chunk
  // A store mapping: lane writes 16B at p*4096 + tid*16. LDS-row r'=p*64+(tid>>2),
  // fp32 row = p*32+(tid>>3), h=(tid>>2)&1, slot=tid&3 -> source chunk:
  const int arow = tid >> 3;                                   // row within pass
  const int acs = (((tid >> 2) & 1) << 2) | ((tid & 3) ^ (arow & 3));

  fx4 acc[4][4] = {};

  auto stage = [&](int buf, int k0) {
#pragma unroll
    for (int p = 0; p < 4; ++p)  // A fp32: 4 passes x 4 KB (32 rows/pass)
      gload16(Afp + (size_t)(m0 + p * 32 + arow) * 1024 + k0 + acs * 4,
              (char*)Al[buf] + p * 4096 + wid * 1024);
    gload16(Bt + (size_t)(n0 + row0) * 1024 + k0 + chx * 8,
            (char*)Bl[buf] + wid * 1024);
    gload16(Bt + (size_t)(n0 + 64 + row0) * 1024 + k0 + chx * 8,
            (char*)Bl[buf] + 4096 + wid * 1024);
  };

#define QSTEP(BUF, T, NW)                                                     \
  do {                                                                       \
    asm volatile("s_waitcnt vmcnt(" #NW ")" ::: "memory");                   \
    __builtin_amdgcn_s_barrier();                                            \
    __builtin_amdgcn_sched_barrier(0);                                       \
    s16x8 afr[4], bfr[4];                                                    \
    _Pragma("unroll") for (int m = 0; m < 4; ++m) {                          \
      const int row = wr * 64 + m * 16 + lr;                                 \
      const int ax = (2 * row + (g >> 1)) * 64 +                             \
                     ((((2 * g) & 3) ^ (row & 3)) << 4);                     \
      fx4 x = *(const fx4*)((const char*)Al[BUF] + ax);                      \
      fx4 y = *(const fx4*)((const char*)Al[BUF] + (ax ^ 16));               \
      u32x4 w;                                                               \
      w[0] = cvt_pk_bf16(x[0], x[1]);                                        \
      w[1] = cvt_pk_bf16(x[2], x[3]);                                        \
      w[2] = cvt_pk_bf16(y[0], y[1]);                                        \
      w[3] = cvt_pk_bf16(y[2], y[3]);                                        \
      afr[m] = __builtin_bit_cast(s16x8, w);                                 \
    }                                                                        \
    _Pragma("unroll") for (int n = 0; n < 4; ++n) {                          \
      const int row = wc * 64 + n * 16 + lr;                                 \
      bfr[n] = *(const s16x8*)((const char*)Bl[BUF] + row * 64 +             \
                               (g ^ ((row >> 1) & 3)) * 16);                 \
    }                                                                        \
    asm volatile("s_waitcnt lgkmcnt(0)" ::: "memory");                       \
    __builtin_amdgcn_sched_barrier(0);                                       \
    __builtin_amdgcn_s_barrier();                                            \
    __builtin_amdgcn_sched_barrier(0);                                       \
    if ((T) + 2 < 32) stage(BUF, ((T) + 2) * 32);                            \
    __builtin_amdgcn_s_setprio(1);                                           \
    _Pragma("unroll") for (int m = 0; m < 4; ++m)                            \
        _Pragma("unroll") for (int n = 0; n < 4; ++n) acc[m][n] =            \
        mfma16(afr[m], bfr[n], acc[m][n]);                                   \
    __builtin_amdgcn_s_setprio(0);                                           \
  } while (0)

  // prologue: fill both buffers (12 loads in flight per wave)
  stage(0, 0);
  stage(1, 32);

#pragma unroll 1
  for (int t = 0; t < 30; t += 2) {
    QSTEP(0, t, 6);
    QSTEP(1, t + 1, 6);
  }
  QSTEP(0, 30, 6);
  QSTEP(1, 31, 0);
#undef QSTEP

  if (vout) {
    // V path: write vt[(b*16+h)*64 + d][s] directly (transpose fused)
#pragma unroll
    for (int n = 0; n < 4; ++n) {
      const int col = n0 + wc * 64 + n * 16 + lr;
      const float bv = bias[col] * bscale;
      const int h = col >> 6, d = col & 63;
#pragma unroll
      for (int m = 0; m < 4; ++m) {
        const int row = m0 + wr * 64 + m * 16 + g * 4;
        const int bb = row >> 11, s = row & 2047;
        u32x2 w;
        w[0] = cvt_pk_bf16(acc[m][n][0] + bv, acc[m][n][1] + bv);
        w[1] = cvt_pk_bf16(acc[m][n][2] + bv, acc[m][n][3] + bv);
        *(u32x2*)(vt + ((size_t)(((bb << 4) | h) * 64 + d)) * 2048 + s) = w;
      }
    }
  } else {
#pragma unroll
    for (int n = 0; n < 4; ++n) {
      const int col = n0 + wc * 64 + n * 16 + lr;
      const float bv = bias[col] * bscale;
#pragma unroll
      for (int m = 0; m < 4; ++m) {
        const int row = m0 + wr * 64 + m * 16 + g * 4;
#pragma unroll
        for (int j = 0; j < 4; ++j)
          store_out(C, (size_t)(row + j) * 1024 + col, acc[m][n][j] + bv);
      }
    }
  }
}

// XCD panel-grouping swizzle: all 8 column-blocks of one A-panel on ONE XCD.
__global__ __launch_bounds__(256, 3) void gemm_qkv_kernel(
    const float* Q, const float* K, const float* V, const u16* Wq, const u16* Wk,
    const u16* Wv, const float* bq, const float* bk, const float* bv, u16* q,
    u16* k, u16* vt) {
  const int hw = blockIdx.x + (blockIdx.y << 3) + (blockIdx.z << 8);
  const int xcd = hw & 7, j = hw >> 3;
  const int x = j & 7;
  const int p = xcd + ((j >> 3) << 3);  // panel 0..95
  const int y = p & 31, z = p >> 5;

  const float* Ap;
  const u16* Bp;
  const float* bp;
  u16* Cp;
  float bs = 1.0f;
  bool vo = false;
  if (z == 0)      { Ap = Q; Bp = Wq; bp = bq; Cp = q; bs = 0.18033688f; }
  else if (z == 1) { Ap = K; Bp = Wk; bp = bk; Cp = k; }
  else             { Ap = V; Bp = Wv; bp = bv; Cp = q; vo = true; }
  gemm_f32_pipe(Ap, Bp, bp, bs, Cp, vt, vo, y * 128, x * 128);
}

// ---------------- counted-vmcnt 3-buffer bf16 GEMM (R14 form) for gemm_out -------
__global__ __launch_bounds__(256, 3) void gemm_out_kernel(const u16* __restrict__ ctx,
                                                          const u16* __restrict__ Wo,
                                                          const float* __restrict__ bo,
                                                          float* __restrict__ out) {
  const int hw = blockIdx.x + (blockIdx.y << 3);
  const int xcd = hw & 7, j = hw >> 3;
  const int x = j & 7;
  const int y = xcd + ((j >> 3) << 3);  // panel 0..31
  const int m0 = y * 128, n0 = x * 128;

  __shared__ u16 Al[3][128 * 32];
  __shared__ u16 Bl[3][128 * 32];
  const int tid = threadIdx.x;
  const int wid = tid >> 6, lane = tid & 63;
  const int g = lane >> 4, lr = lane & 15;
  const int wr = wid >> 1, wc = wid & 1;
  const int row0 = tid >> 2, ch = tid & 3;
  const int chx = ch ^ ((row0 >> 1) & 3);

  fx4 acc[4][4] = {};

  auto stage = [&](u16* Ab, u16* Bb, int k0) {
    gload16(ctx + (size_t)(m0 + row0) * 1024 + k0 + chx * 8, (char*)Ab + wid * 1024);
    gload16(ctx + (size_t)(m0 + 64 + row0) * 1024 + k0 + chx * 8,
            (char*)Ab + 4096 + wid * 1024);
    gload16(Wo + (size_t)(n0 + row0) * 1024 + k0 + chx * 8, (char*)Bb + wid * 1024);
    gload16(Wo + (size_t)(n0 + 64 + row0) * 1024 + k0 + chx * 8,
            (char*)Bb + 4096 + wid * 1024);
  };

#define GSTEP(BUF, T, NW)                                                     \
  do {                                                                        \
    asm volatile("s_waitcnt vmcnt(" #NW ")" ::: "memory");                    \
    __builtin_amdgcn_s_barrier();                                             \
    __builtin_amdgcn_sched_barrier(0);                                        \
    s16x8 afr[4], bfr[4];                                                     \
    _Pragma("unroll") for (int m = 0; m < 4; ++m) {                           \
      const int row = wr * 64 + m * 16 + lr;                                  \
      afr[m] = *(const s16x8*)((const char*)Al[BUF] + row * 64 +              \
                               (g ^ ((row >> 1) & 3)) * 16);                  \
    }                                                                         \
    _Pragma("unroll") for (int n = 0; n < 4; ++n) {                           \
      const int row = wc * 64 + n * 16 + lr;                                  \
      bfr[n] = *(const s16x8*)((const char*)Bl[BUF] + row * 64 +              \
                               (g ^ ((row >> 1) & 3)) * 16);                  \
    }                                                                         \
    asm volatile("s_waitcnt lgkmcnt(0)" ::: "memory");                        \
    __builtin_amdgcn_sched_barrier(0);                                        \
    __builtin_amdgcn_s_barrier();                                             \
    __builtin_amdgcn_sched_barrier(0);                                        \
    if ((T) + 3 < 32) stage(Al[BUF], Bl[BUF], ((T) + 3) * 32);                \
    __builtin_amdgcn_s_setprio(1);                                            \
    _Pragma("unroll") for (int m = 0; m < 4; ++m)                             \
        _Pragma("unroll") for (int n = 0; n < 4; ++n) acc[m][n] =             \
        mfma16(afr[m], bfr[n], acc[m][n]);                                    \
    __builtin_amdgcn_s_setprio(0);                                            \
  } while (0)

  stage(Al[0], Bl[0], 0);
  stage(Al[1], Bl[1], 32);
  stage(Al[2], Bl[2], 64);

#pragma unroll 1
  for (int t = 0; t < 30; t += 3) {
    GSTEP(0, t, 8);
    GSTEP(1, t + 1, 8);
    GSTEP(2, t + 2, 8);
  }
  GSTEP(0, 30, 4);
  GSTEP(1, 31, 0);
#undef GSTEP

#pragma unroll
  for (int n = 0; n < 4; ++n) {
    const int col = n0 + wc * 64 + n * 16 + lr;
    const float bv = bo[col];
#pragma unroll
    for (int m = 0; m < 4; ++m) {
      const int row = m0 + wr * 64 + m * 16 + g * 4;
#pragma unroll
      for (int j = 0; j < 4; ++j)
        out[(size_t)(row + j) * 1024 + col] = acc[m][n][j] + bv;
    }
  }
}

// ---------------- flash attention: 2 q-groups/wave, counted-vmcnt pipeline -------
// R18/R20 form (session best: attn ~51.5 us). 4 waves x 32 q = 128 q/block;
// 512 blocks (2/CU, 8 waves/CU); 48 KB LDS. Each kf/vf b128 read feeds TWO
// q-groups' MFMAs. Counted-vmcnt ASTEP (never 0 mid-loop), max-free log2
// softmax, XCD bh-grouping (FETCH ~12 MB).
__global__ __launch_bounds__(256, 2) void attn_kernel(const u16* __restrict__ qb,
                                                      const u16* __restrict__ kb,
                                                      const u16* __restrict__ vt,
                                                      u16* __restrict__ ctx) {
  __shared__ u16 Kl[2][64 * 64];  // 8 KB each
  __shared__ u16 Vl[2][64 * 64];
  __shared__ u16 Pl[4][32 * 64];  // per-wave P scratch [q=32][kv=64], 4 KB each

  const int tid = threadIdx.x, wid = tid >> 6, lane = tid & 63;
  const int g = lane >> 4, lr = lane & 15;
  const int rswz = (lr & 7) * 8;   // K/V read swizzle (u16 units)
  const int pswz = (lr & 7) * 16;  // P scratch swizzle (byte units, 16B grain)
  char* Pb = (char*)&Pl[wid][0];

  // XCD bh-grouping: hw%8 = XCD; 4 bh per XCD; 16 q-tiles of 128 per bh
  const int hw = blockIdx.x;
  const int xcd = hw & 7, slot = hw >> 3;  // slot 0..63
  const int bh = xcd * 4 + (slot >> 4);
  const int b = bh >> 4, h = bh & 15;
  const int q0 = (slot & 15) * 128;

  // Q fragments: rows q0 + wid*32 + qg*16 + lr, k = ks*32 + g*8
  const u16* qp = qb + ((size_t)(b * S_LEN + q0 + wid * 32 + lr)) * DM + h * HD;
  s16x8 aq0[2], aq1[2];
  aq0[0] = *(const s16x8*)(qp + g * 8);
  aq0[1] = *(const s16x8*)(qp + 32 + g * 8);
  aq1[0] = *(const s16x8*)(qp + (size_t)16 * DM + g * 8);
  aq1[1] = *(const s16x8*)(qp + (size_t)16 * DM + 32 + g * 8);

  fx4 accO0[4] = {}, accO1[4] = {};
  float lrun0 = 0.f, lrun1 = 0.f;

  // staging: 64 rows x 8 chunks (8 bf16) per half-tile; source chunk pre-swizzled
  const int srow = tid >> 3, sch = tid & 7;
  const int schx = sch ^ (srow & 7);
  const u16* kbase = kb + ((size_t)b * S_LEN) * DM + h * HD;
  const u16* vtbase = vt + ((size_t)bh * 64) * S_LEN;

#define STAGE(buf, kv)                                                             \
  do {                                                                             \
    gload16(kbase + (size_t)((kv) + srow) * DM + schx * 8,                         \
            (char*)Kl[buf] + wid * 1024);                                          \
    gload16(kbase + (size_t)((kv) + 32 + srow) * DM + schx * 8,                    \
            (char*)Kl[buf] + 4096 + wid * 1024);                                   \
    gload16(vtbase + (size_t)srow * S_LEN + (kv) + schx * 8,                       \
            (char*)Vl[buf] + wid * 1024);                                          \
    gload16(vtbase + (size_t)(32 + srow) * S_LEN + (kv) + schx * 8,                \
            (char*)Vl[buf] + 4096 + wid * 1024);                                   \
  } while (0)

// One attn pipeline step on buffer BUF for tile T; NW = loads allowed in flight.
#define ASTEP(BUF, T, NW)                                                          \
  do {                                                                             \
    asm volatile("s_waitcnt vmcnt(" #NW ")" ::: "memory");                         \
    __builtin_amdgcn_s_barrier();                                                  \
    __builtin_amdgcn_sched_barrier(0);                                             \
    fx4 s0[4] = {}, s1[4] = {};                                                    \
    s16x8 vf0[4], vf1[4];                                                          \
    __builtin_amdgcn_s_setprio(1);                                                 \
    _Pragma("unroll") for (int ks = 0; ks < 2; ++ks) {                             \
      _Pragma("unroll") for (int c = 0; c < 4; ++c) {                              \
        s16x8 kf = *(const s16x8*)(Kl[BUF] + (c * 16 + lr) * 64 +                  \
                                   ((ks * 32 + g * 8) ^ rswz));                    \
        s0[c] = mfma16(kf, ks ? aq0[1] : aq0[0], s0[c]);                           \
        s1[c] = mfma16(kf, ks ? aq1[1] : aq1[0], s1[c]);                           \
      }                                                                            \
    }                                                                              \
    __builtin_amdgcn_s_setprio(0);                                                 \
    _Pragma("unroll") for (int c = 0; c < 4; ++c) {                                \
      vf0[c] = *(const s16x8*)(Vl[BUF] + (c * 16 + lr) * 64 + ((g * 8) ^ rswz));   \
      vf1[c] =                                                                     \
          *(const s16x8*)(Vl[BUF] + (c * 16 + lr) * 64 + ((32 + g * 8) ^ rswz));   \
    }                                                                              \
    asm volatile("s_waitcnt lgkmcnt(0)" ::: "memory");                             \
    __builtin_amdgcn_sched_barrier(0);                                             \
    __builtin_amdgcn_s_barrier();                                                  \
    __builtin_amdgcn_sched_barrier(0);                                             \
    if ((T) + 2 < 32) STAGE(BUF, ((T) + 2) * 64);                                  \
    /* softmax both q-groups: p = exp2(s), per-lane partials (independent ILP) */  \
    _Pragma("unroll") for (int c = 0; c < 4; ++c)                                  \
        _Pragma("unroll") for (int j = 0; j < 4; ++j) {                            \
      s0[c][j] = __builtin_amdgcn_exp2f(s0[c][j]);                                 \
      s1[c][j] = __builtin_amdgcn_exp2f(s1[c][j]);                                 \
    }                                                                              \
    lrun0 += ((s0[0][0] + s0[0][1]) + (s0[0][2] + s0[0][3])) +                     \
             ((s0[1][0] + s0[1][1]) + (s0[1][2] + s0[1][3])) +                     \
             ((s0[2][0] + s0[2][1]) + (s0[2][2] + s0[2][3])) +                     \
             ((s0[3][0] + s0[3][1]) + (s0[3][2] + s0[3][3]));                      \
    lrun1 += ((s1[0][0] + s1[0][1]) + (s1[0][2] + s1[0][3])) +                     \
             ((s1[1][0] + s1[1][1]) + (s1[1][2] + s1[1][3])) +                     \
             ((s1[2][0] + s1[2][1]) + (s1[2][2] + s1[2][3])) +                     \
             ((s1[3][0] + s1[3][1]) + (s1[3][2] + s1[3][3]));                      \
    /* P -> per-wave LDS, packed b64 writes (rows lr and 16+lr) */                 \
    _Pragma("unroll") for (int c = 0; c < 4; ++c) {                                \
      u32x2 w0, w1;                                                                \
      w0[0] = cvt_pk_bf16(s0[c][0], s0[c][1]);                                     \
      w0[1] = cvt_pk_bf16(s0[c][2], s0[c][3]);                                     \
      w1[0] = cvt_pk_bf16(s1[c][0], s1[c][1]);                                     \
      w1[1] = cvt_pk_bf16(s1[c][2], s1[c][3]);                                     \
      *(u32x2*)(Pb + lr * 128 + ((c * 32 + g * 8) ^ pswz)) = w0;                   \
      *(u32x2*)(Pb + (16 + lr) * 128 + ((c * 32 + g * 8) ^ pswz)) = w1;            \
    }                                                                              \
    /* PV both q-groups from shared vf regs */                                     \
    __builtin_amdgcn_s_setprio(1);                                                 \
    {                                                                              \
      s16x8 pb00 = *(const s16x8*)(Pb + lr * 128 + ((g * 16) ^ pswz));             \
      s16x8 pb01 = *(const s16x8*)(Pb + lr * 128 + ((64 + g * 16) ^ pswz));        \
      s16x8 pb10 = *(const s16x8*)(Pb + (16 + lr) * 128 + ((g * 16) ^ pswz));      \
      s16x8 pb11 =                                                                 \
          *(const s16x8*)(Pb + (16 + lr) * 128 + ((64 + g * 16) ^ pswz));          \
      _Pragma("unroll") for (int c = 0; c < 4; ++c) {                              \
        accO0[c] = mfma16(vf0[c], pb00, accO0[c]);                                 \
        accO0[c] = mfma16(vf1[c], pb01, accO0[c]);                                 \
        accO1[c] = mfma16(vf0[c], pb10, accO1[c]);                                 \
        accO1[c] = mfma16(vf1[c], pb11, accO1[c]);                                 \
      }                                                                            \
    }                                                                              \
    __builtin_amdgcn_s_setprio(0);                                                 \
  } while (0)

  // prologue: fill both buffers (8 loads in flight)
  STAGE(0, 0);
  STAGE(1, 64);

#pragma unroll 1
  for (int t = 0; t < 30; t += 2) {
    ASTEP(0, t, 4);
    ASTEP(1, t + 1, 4);
  }
  ASTEP(0, 30, 4);
  ASTEP(1, 31, 0);
#undef ASTEP
#undef STAGE

  // epilogue: reduce lrun across the 4 groups, then O^T[d][q] -> ctx[b,q,h,d]
  lrun0 += __shfl_xor(lrun0, 16);
  lrun0 += __shfl_xor(lrun0, 32);
  lrun1 += __shfl_xor(lrun1, 16);
  lrun1 += __shfl_xor(lrun1, 32);
  const float inv0 = 1.0f / lrun0;
  const float inv1 = 1.0f / lrun1;
  u16* op0 = ctx + ((size_t)(b * S_LEN + q0 + wid * 32 + lr)) * DM + h * HD;
  u16* op1 = op0 + (size_t)16 * DM;
#pragma unroll
  for (int c = 0; c < 4; ++c) {
    u32x2 w0, w1;
    w0[0] = cvt_pk_bf16(accO0[c][0] * inv0, accO0[c][1] * inv0);
    w0[1] = cvt_pk_bf16(accO0[c][2] * inv0, accO0[c][3] * inv0);
    w1[0] = cvt_pk_bf16(accO1[c][0] * inv1, accO1[c][1] * inv1);
    w1[1] = cvt_pk_bf16(accO1[c][2] * inv1, accO1[c][3] * inv1);
    *(u32x2*)(op0 + c * 16 + g * 4) = w0;
    *(u32x2*)(op1 + c * 16 + g * 4) = w1;
  }
}

// ---------------- launcher ----------------
extern "C" void kernel_launch(void* const* d_in, const int* in_sizes, int n_in,
                              void* d_out, int out_size, void* d_ws, size_t ws_size,
                              hipStream_t stream) {
  const float* Q = (const float*)d_in[0];
  const float* K = (const float*)d_in[1];
  const float* V = (const float*)d_in[2];
  const float* Wq = (const float*)d_in[3];
  const float* bq = (const float*)d_in[4];
  const float* Wk = (const float*)d_in[5];
  const float* bk = (const float*)d_in[6];
  const float* Wv = (const float*)d_in[7];
  const float* bv = (const float*)d_in[8];
  const float* Wo = (const float*)d_in[9];
  const float* bo = (const float*)d_in[10];
  float* out = (float*)d_out;

  char* ws = (char*)d_ws;
  const size_t SZ_T = (size_t)NB * S_LEN * DM * 2;  // 8.39 MB (bf16 tensor)
  const size_t SZ_W = (size_t)DM * DM * 2;          // 2.10 MB (bf16 weight)

  u16* Wqb = (u16*)(ws);
  u16* Wkb = (u16*)(ws + SZ_W);
  u16* Wvb = (u16*)(ws + 2 * SZ_W);
  u16* Wob = (u16*)(ws + 3 * SZ_W);
  u16* qb  = (u16*)(ws + 4 * SZ_W);
  u16* kb  = (u16*)(ws + 4 * SZ_W + SZ_T);
  u16* vtb = (u16*)(ws + 4 * SZ_W + 2 * SZ_T);
  u16* ctx = (u16*)(ws + 4 * SZ_W + 3 * SZ_T);  // total ~42 MB

  cvt_w_kernel<<<2048, 256, 0, stream>>>(Wq, Wk, Wv, Wo, Wqb, Wkb, Wvb, Wob);

  gemm_qkv_kernel<<<dim3(8, 32, 3), 256, 0, stream>>>(Q, K, V, Wqb, Wkb, Wvb,
                                                      bq, bk, bv, qb, kb, vtb);

  attn_kernel<<<512, 256, 0, stream>>>(qb, kb, vtb, ctx);

  gemm_out_kernel<<<dim3(8, 32), 256, 0, stream>>>(ctx, Wob, bo, out);
}

// Round 23
// 107.356 us; speedup vs baseline: 1.0219x; 1.0219x over previous
//
#include <hip/hip_runtime.h>

#define S_LEN 2048
#define DM 1024
#define NH 16
#define HD 64
#define NB 2

typedef unsigned short u16;
typedef __attribute__((ext_vector_type(8))) short s16x8;
typedef __attribute__((ext_vector_type(8))) unsigned short u16x8;
typedef __attribute__((ext_vector_type(4))) float fx4;
typedef __attribute__((ext_vector_type(2))) unsigned u32x2;
typedef __attribute__((ext_vector_type(4))) unsigned u32x4;

__device__ __forceinline__ u16 f2bf(float f) {
  unsigned u = __builtin_bit_cast(unsigned, f);
  return (u16)((u + 0x7FFFu + ((u >> 16) & 1u)) >> 16);
}

// packed fp32x2 -> bf16x2 (low = a, high = b); no builtin on gfx950 (T12 recipe)
__device__ __forceinline__ unsigned cvt_pk_bf16(float a, float b) {
  unsigned r;
  asm("v_cvt_pk_bf16_f32 %0, %1, %2" : "=v"(r) : "v"(a), "v"(b));
  return r;
}

__device__ __forceinline__ void gload16(const void* g, void* l) {
  __builtin_amdgcn_global_load_lds(
      (const __attribute__((address_space(1))) unsigned*)g,
      (__attribute__((address_space(3))) unsigned*)l, 16, 0, 0);
}

__device__ __forceinline__ fx4 mfma16(s16x8 a, s16x8 b, fx4 c) {
  return __builtin_amdgcn_mfma_f32_16x16x32_bf16(a, b, c, 0, 0, 0);
}

// ---------------- fp32 -> bf16 convert: WEIGHTS ONLY ----------------
// Wq gets 0.125 (1/sqrt(hd)) * 1.44269504 (log2 e): scores land in log2 domain.
__global__ __launch_bounds__(256) void cvt_w_kernel(
    const float* __restrict__ Wq, const float* __restrict__ Wk,
    const float* __restrict__ Wv, const float* __restrict__ Wo,
    u16* __restrict__ Wqb, u16* __restrict__ Wkb, u16* __restrict__ Wvb,
    u16* __restrict__ Wob) {
  const int blk = blockIdx.x;
  const float* src;
  u16* dst;
  float scale = 1.0f;
  int off;
  if (blk < 512)       { src = Wq; dst = Wqb; off = blk;        scale = 0.18033688f; }
  else if (blk < 1024) { src = Wk; dst = Wkb; off = blk - 512;  }
  else if (blk < 1536) { src = Wv; dst = Wvb; off = blk - 1024; }
  else                 { src = Wo; dst = Wob; off = blk - 1536; }
  const int i = (off * 256 + (int)threadIdx.x) * 8;
  fx4 a = *(const fx4*)(src + i);
  fx4 b = *(const fx4*)(src + i + 4);
  u16x8 o;
  o[0] = f2bf(a[0] * scale); o[1] = f2bf(a[1] * scale);
  o[2] = f2bf(a[2] * scale); o[3] = f2bf(a[3] * scale);
  o[4] = f2bf(b[0] * scale); o[5] = f2bf(b[1] * scale);
  o[6] = f2bf(b[2] * scale); o[7] = f2bf(b[3] * scale);
  *(u16x8*)(dst + i) = o;
}

__device__ __forceinline__ void store_out(u16* C, size_t idx, float v) { C[idx] = f2bf(v); }
__device__ __forceinline__ void store_out(float* C, size_t idx, float v) { C[idx] = v; }

// ---------------- qkv GEMM: fp32 A, 2-buffer counted-vmcnt pipeline ----------------
// C[m,n] = sum_k A_fp32[m,k]*Bt_bf16[n,k] + bias. 128x128, BK=32, 4 waves.
// A staged RAW fp32 via global_load_lds (no cvt pass, no reg round-trip):
// 4 passes x 16B/lane; stored chunk j holds source chunk j^(row&7) (rule 21
// involution). Frags: 2 fx4 reads + 4 cvt_pk (hidden under MFMA).
// Pipeline = attn's proven ASTEP shape: vmcnt(6) (next buffer's 6 loads stay in
// flight) -> barrier -> frag reads -> lgkm -> barrier -> re-stage -> MFMA.
// LDS 2 x (16+8) KB = 48 KB -> 3 blocks/CU. (R21 measured-best configuration.)
__device__ __forceinline__ void gemm_f32_pipe(const float* __restrict__ Afp,
                                              const u16* __restrict__ Bt,
                                              const float* __restrict__ bias,
                                              float bscale, u16* __restrict__ C,
                                              u16* __restrict__ vt, bool vout,
                                              int m0, int n0) {
  __shared__ u16 Al[2][128 * 64];  // fp32 tile as u16 words: 16 KB each
  __shared__ u16 Bl[2][128 * 32];  // 8 KB each
  const int tid = threadIdx.x;
  const int wid = tid >> 6, lane = tid & 63;
  const int g = lane >> 4, lr = lane & 15;
  const int wr = wid >> 1, wc = wid & 1;
  const int row0 = tid >> 2, ch = tid & 3;  // B: 128 rows x 4 chunks(16B)
  const int chx = ch ^ ((row0 >> 1) & 3);   // B pre-swizzled source chunk
  const int arow = tid >> 3;                // A: 32 rows/pass x 8 chunks(16B)
  const int acs = (tid & 7) ^ (arow & 7);   // A pre-swizzled source chunk

  fx4 acc[4][4] = {};

  auto stage = [&](int buf, int k0) {
#pragma unroll
    for (int p = 0; p < 4; ++p)  // A fp32: 4 passes x 4 KB
      gload16(Afp + (size_t)(m0 + p * 32 + arow) * 1024 + k0 + acs * 4,
              (char*)Al[buf] + p * 4096 + wid * 1024);
    gload16(Bt + (size_t)(n0 + row0) * 1024 + k0 + chx * 8,
            (char*)Bl[buf] + wid * 1024);
    gload16(Bt + (size_t)(n0 + 64 + row0) * 1024 + k0 + chx * 8,
            (char*)Bl[buf] + 4096 + wid * 1024);
  };

#define QSTEP(BUF, T, NW)                                                     \
  do {                                                                       \
    asm volatile("s_waitcnt vmcnt(" #NW ")" ::: "memory");                   \
    __builtin_amdgcn_s_barrier();                                            \
    __builtin_amdgcn_sched_barrier(0);                                       \
    s16x8 afr[4], bfr[4];                                                    \
    _Pragma("unroll") for (int m = 0; m < 4; ++m) {                          \
      const int row = wr * 64 + m * 16 + lr;                                 \
      fx4 x = *(const fx4*)((const char*)Al[BUF] + row * 128 +               \
                            ((2 * g) ^ (lr & 7)) * 16);                      \
      fx4 y = *(const fx4*)((const char*)Al[BUF] + row * 128 +               \
                            ((2 * g + 1) ^ (lr & 7)) * 16);                  \
      u32x4 w;                                                               \
      w[0] = cvt_pk_bf16(x[0], x[1]);                                        \
      w[1] = cvt_pk_bf16(x[2], x[3]);                                        \
      w[2] = cvt_pk_bf16(y[0], y[1]);                                        \
      w[3] = cvt_pk_bf16(y[2], y[3]);                                        \
      afr[m] = __builtin_bit_cast(s16x8, w);                                 \
    }                                                                        \
    _Pragma("unroll") for (int n = 0; n < 4; ++n) {                          \
      const int row = wc * 64 + n * 16 + lr;                                 \
      bfr[n] = *(const s16x8*)((const char*)Bl[BUF] + row * 64 +             \
                               (g ^ ((row >> 1) & 3)) * 16);                 \
    }                                                                        \
    asm volatile("s_waitcnt lgkmcnt(0)" ::: "memory");                       \
    __builtin_amdgcn_sched_barrier(0);                                       \
    __builtin_amdgcn_s_barrier();                                            \
    __builtin_amdgcn_sched_barrier(0);                                       \
    if ((T) + 2 < 32) stage(BUF, ((T) + 2) * 32);                            \
    __builtin_amdgcn_s_setprio(1);                                           \
    _Pragma("unroll") for (int m = 0; m < 4; ++m)                            \
        _Pragma("unroll") for (int n = 0; n < 4; ++n) acc[m][n] =            \
        mfma16(afr[m], bfr[n], acc[m][n]);                                   \
    __builtin_amdgcn_s_setprio(0);                                           \
  } while (0)

  // prologue: fill both buffers (12 loads in flight per wave)
  stage(0, 0);
  stage(1, 32);

#pragma unroll 1
  for (int t = 0; t < 30; t += 2) {
    QSTEP(0, t, 6);
    QSTEP(1, t + 1, 6);
  }
  QSTEP(0, 30, 6);
  QSTEP(1, 31, 0);
#undef QSTEP

  if (vout) {
    // V path: write vt[(b*16+h)*64 + d][s] directly (transpose fused)
#pragma unroll
    for (int n = 0; n < 4; ++n) {
      const int col = n0 + wc * 64 + n * 16 + lr;
      const float bv = bias[col] * bscale;
      const int h = col >> 6, d = col & 63;
#pragma unroll
      for (int m = 0; m < 4; ++m) {
        const int row = m0 + wr * 64 + m * 16 + g * 4;
        const int bb = row >> 11, s = row & 2047;
        u32x2 w;
        w[0] = cvt_pk_bf16(acc[m][n][0] + bv, acc[m][n][1] + bv);
        w[1] = cvt_pk_bf16(acc[m][n][2] + bv, acc[m][n][3] + bv);
        *(u32x2*)(vt + ((size_t)(((bb << 4) | h) * 64 + d)) * 2048 + s) = w;
      }
    }
  } else {
#pragma unroll
    for (int n = 0; n < 4; ++n) {
      const int col = n0 + wc * 64 + n * 16 + lr;
      const float bv = bias[col] * bscale;
#pragma unroll
      for (int m = 0; m < 4; ++m) {
        const int row = m0 + wr * 64 + m * 16 + g * 4;
#pragma unroll
        for (int j = 0; j < 4; ++j)
          store_out(C, (size_t)(row + j) * 1024 + col, acc[m][n][j] + bv);
      }
    }
  }
}

// XCD panel-grouping swizzle: all 8 column-blocks of one A-panel on ONE XCD.
__global__ __launch_bounds__(256, 3) void gemm_qkv_kernel(
    const float* Q, const float* K, const float* V, const u16* Wq, const u16* Wk,
    const u16* Wv, const float* bq, const float* bk, const float* bv, u16* q,
    u16* k, u16* vt) {
  const int hw = blockIdx.x + (blockIdx.y << 3) + (blockIdx.z << 8);
  const int xcd = hw & 7, j = hw >> 3;
  const int x = j & 7;
  const int p = xcd + ((j >> 3) << 3);  // panel 0..95
  const int y = p & 31, z = p >> 5;

  const float* Ap;
  const u16* Bp;
  const float* bp;
  u16* Cp;
  float bs = 1.0f;
  bool vo = false;
  if (z == 0)      { Ap = Q; Bp = Wq; bp = bq; Cp = q; bs = 0.18033688f; }
  else if (z == 1) { Ap = K; Bp = Wk; bp = bk; Cp = k; }
  else             { Ap = V; Bp = Wv; bp = bv; Cp = q; vo = true; }
  gemm_f32_pipe(Ap, Bp, bp, bs, Cp, vt, vo, y * 128, x * 128);
}

// ---------------- counted-vmcnt 3-buffer bf16 GEMM (R14 form) for gemm_out -------
__global__ __launch_bounds__(256, 3) void gemm_out_kernel(const u16* __restrict__ ctx,
                                                          const u16* __restrict__ Wo,
                                                          const float* __restrict__ bo,
                                                          float* __restrict__ out) {
  const int hw = blockIdx.x + (blockIdx.y << 3);
  const int xcd = hw & 7, j = hw >> 3;
  const int x = j & 7;
  const int y = xcd + ((j >> 3) << 3);  // panel 0..31
  const int m0 = y * 128, n0 = x * 128;

  __shared__ u16 Al[3][128 * 32];
  __shared__ u16 Bl[3][128 * 32];
  const int tid = threadIdx.x;
  const int wid = tid >> 6, lane = tid & 63;
  const int g = lane >> 4, lr = lane & 15;
  const int wr = wid >> 1, wc = wid & 1;
  const int row0 = tid >> 2, ch = tid & 3;
  const int chx = ch ^ ((row0 >> 1) & 3);

  fx4 acc[4][4] = {};

  auto stage = [&](u16* Ab, u16* Bb, int k0) {
    gload16(ctx + (size_t)(m0 + row0) * 1024 + k0 + chx * 8, (char*)Ab + wid * 1024);
    gload16(ctx + (size_t)(m0 + 64 + row0) * 1024 + k0 + chx * 8,
            (char*)Ab + 4096 + wid * 1024);
    gload16(Wo + (size_t)(n0 + row0) * 1024 + k0 + chx * 8, (char*)Bb + wid * 1024);
    gload16(Wo + (size_t)(n0 + 64 + row0) * 1024 + k0 + chx * 8,
            (char*)Bb + 4096 + wid * 1024);
  };

#define GSTEP(BUF, T, NW)                                                     \
  do {                                                                        \
    asm volatile("s_waitcnt vmcnt(" #NW ")" ::: "memory");                    \
    __builtin_amdgcn_s_barrier();                                             \
    __builtin_amdgcn_sched_barrier(0);                                        \
    s16x8 afr[4], bfr[4];                                                     \
    _Pragma("unroll") for (int m = 0; m < 4; ++m) {                           \
      const int row = wr * 64 + m * 16 + lr;                                  \
      afr[m] = *(const s16x8*)((const char*)Al[BUF] + row * 64 +              \
                               (g ^ ((row >> 1) & 3)) * 16);                  \
    }                                                                         \
    _Pragma("unroll") for (int n = 0; n < 4; ++n) {                           \
      const int row = wc * 64 + n * 16 + lr;                                  \
      bfr[n] = *(const s16x8*)((const char*)Bl[BUF] + row * 64 +              \
                               (g ^ ((row >> 1) & 3)) * 16);                  \
    }                                                                         \
    asm volatile("s_waitcnt lgkmcnt(0)" ::: "memory");                        \
    __builtin_amdgcn_sched_barrier(0);                                        \
    __builtin_amdgcn_s_barrier();                                             \
    __builtin_amdgcn_sched_barrier(0);                                        \
    if ((T) + 3 < 32) stage(Al[BUF], Bl[BUF], ((T) + 3) * 32);                \
    __builtin_amdgcn_s_setprio(1);                                            \
    _Pragma("unroll") for (int m = 0; m < 4; ++m)                             \
        _Pragma("unroll") for (int n = 0; n < 4; ++n) acc[m][n] =             \
        mfma16(afr[m], bfr[n], acc[m][n]);                                    \
    __builtin_amdgcn_s_setprio(0);                                            \
  } while (0)

  stage(Al[0], Bl[0], 0);
  stage(Al[1], Bl[1], 32);
  stage(Al[2], Bl[2], 64);

#pragma unroll 1
  for (int t = 0; t < 30; t += 3) {
    GSTEP(0, t, 8);
    GSTEP(1, t + 1, 8);
    GSTEP(2, t + 2, 8);
  }
  GSTEP(0, 30, 4);
  GSTEP(1, 31, 0);
#undef GSTEP

#pragma unroll
  for (int n = 0; n < 4; ++n) {
    const int col = n0 + wc * 64 + n * 16 + lr;
    const float bv = bo[col];
#pragma unroll
    for (int m = 0; m < 4; ++m) {
      const int row = m0 + wr * 64 + m * 16 + g * 4;
#pragma unroll
      for (int j = 0; j < 4; ++j)
        out[(size_t)(row + j) * 1024 + col] = acc[m][n][j] + bv;
    }
  }
}

// ---------------- flash attention: 2 q-groups/wave, counted-vmcnt pipeline -------
// R18/R20 form (session best: attn ~51.5 us). 4 waves x 32 q = 128 q/block;
// 512 blocks (2/CU, 8 waves/CU); 48 KB LDS. Each kf/vf b128 read feeds TWO
// q-groups' MFMAs. Counted-vmcnt ASTEP (never 0 mid-loop), max-free log2
// softmax, XCD bh-grouping (FETCH ~12 MB).
__global__ __launch_bounds__(256, 2) void attn_kernel(const u16* __restrict__ qb,
                                                      const u16* __restrict__ kb,
                                                      const u16* __restrict__ vt,
                                                      u16* __restrict__ ctx) {
  __shared__ u16 Kl[2][64 * 64];  // 8 KB each
  __shared__ u16 Vl[2][64 * 64];
  __shared__ u16 Pl[4][32 * 64];  // per-wave P scratch [q=32][kv=64], 4 KB each

  const int tid = threadIdx.x, wid = tid >> 6, lane = tid & 63;
  const int g = lane >> 4, lr = lane & 15;
  const int rswz = (lr & 7) * 8;   // K/V read swizzle (u16 units)
  const int pswz = (lr & 7) * 16;  // P scratch swizzle (byte units, 16B grain)
  char* Pb = (char*)&Pl[wid][0];

  // XCD bh-grouping: hw%8 = XCD; 4 bh per XCD; 16 q-tiles of 128 per bh
  const int hw = blockIdx.x;
  const int xcd = hw & 7, slot = hw >> 3;  // slot 0..63
  const int bh = xcd * 4 + (slot >> 4);
  const int b = bh >> 4, h = bh & 15;
  const int q0 = (slot & 15) * 128;

  // Q fragments: rows q0 + wid*32 + qg*16 + lr, k = ks*32 + g*8
  const u16* qp = qb + ((size_t)(b * S_LEN + q0 + wid * 32 + lr)) * DM + h * HD;
  s16x8 aq0[2], aq1[2];
  aq0[0] = *(const s16x8*)(qp + g * 8);
  aq0[1] = *(const s16x8*)(qp + 32 + g * 8);
  aq1[0] = *(const s16x8*)(qp + (size_t)16 * DM + g * 8);
  aq1[1] = *(const s16x8*)(qp + (size_t)16 * DM + 32 + g * 8);

  fx4 accO0[4] = {}, accO1[4] = {};
  float lrun0 = 0.f, lrun1 = 0.f;

  // staging: 64 rows x 8 chunks (8 bf16) per half-tile; source chunk pre-swizzled
  const int srow = tid >> 3, sch = tid & 7;
  const int schx = sch ^ (srow & 7);
  const u16* kbase = kb + ((size_t)b * S_LEN) * DM + h * HD;
  const u16* vtbase = vt + ((size_t)bh * 64) * S_LEN;

#define STAGE(buf, kv)                                                             \
  do {                                                                             \
    gload16(kbase + (size_t)((kv) + srow) * DM + schx * 8,                         \
            (char*)Kl[buf] + wid * 1024);                                          \
    gload16(kbase + (size_t)((kv) + 32 + srow) * DM + schx * 8,                    \
            (char*)Kl[buf] + 4096 + wid * 1024);                                   \
    gload16(vtbase + (size_t)srow * S_LEN + (kv) + schx * 8,                       \
            (char*)Vl[buf] + wid * 1024);                                          \
    gload16(vtbase + (size_t)(32 + srow) * S_LEN + (kv) + schx * 8,                \
            (char*)Vl[buf] + 4096 + wid * 1024);                                   \
  } while (0)

// One attn pipeline step on buffer BUF for tile T; NW = loads allowed in flight.
#define ASTEP(BUF, T, NW)                                                          \
  do {                                                                             \
    asm volatile("s_waitcnt vmcnt(" #NW ")" ::: "memory");                         \
    __builtin_amdgcn_s_barrier();                                                  \
    __builtin_amdgcn_sched_barrier(0);                                             \
    fx4 s0[4] = {}, s1[4] = {};                                                    \
    s16x8 vf0[4], vf1[4];                                                          \
    __builtin_amdgcn_s_setprio(1);                                                 \
    _Pragma("unroll") for (int ks = 0; ks < 2; ++ks) {                             \
      _Pragma("unroll") for (int c = 0; c < 4; ++c) {                              \
        s16x8 kf = *(const s16x8*)(Kl[BUF] + (c * 16 + lr) * 64 +                  \
                                   ((ks * 32 + g * 8) ^ rswz));                    \
        s0[c] = mfma16(kf, ks ? aq0[1] : aq0[0], s0[c]);                           \
        s1[c] = mfma16(kf, ks ? aq1[1] : aq1[0], s1[c]);                           \
      }                                                                            \
    }                                                                              \
    __builtin_amdgcn_s_setprio(0);                                                 \
    _Pragma("unroll") for (int c = 0; c < 4; ++c) {                                \
      vf0[c] = *(const s16x8*)(Vl[BUF] + (c * 16 + lr) * 64 + ((g * 8) ^ rswz));   \
      vf1[c] =                                                                     \
          *(const s16x8*)(Vl[BUF] + (c * 16 + lr) * 64 + ((32 + g * 8) ^ rswz));   \
    }                                                                              \
    asm volatile("s_waitcnt lgkmcnt(0)" ::: "memory");                             \
    __builtin_amdgcn_sched_barrier(0);                                             \
    __builtin_amdgcn_s_barrier();                                                  \
    __builtin_amdgcn_sched_barrier(0);                                             \
    if ((T) + 2 < 32) STAGE(BUF, ((T) + 2) * 64);                                  \
    /* softmax both q-groups: p = exp2(s), per-lane partials (independent ILP) */  \
    _Pragma("unroll") for (int c = 0; c < 4; ++c)                                  \
        _Pragma("unroll") for (int j = 0; j < 4; ++j) {                            \
      s0[c][j] = __builtin_amdgcn_exp2f(s0[c][j]);                                 \
      s1[c][j] = __builtin_amdgcn_exp2f(s1[c][j]);                                 \
    }                                                                              \
    lrun0 += ((s0[0][0] + s0[0][1]) + (s0[0][2] + s0[0][3])) +                     \
             ((s0[1][0] + s0[1][1]) + (s0[1][2] + s0[1][3])) +                     \
             ((s0[2][0] + s0[2][1]) + (s0[2][2] + s0[2][3])) +                     \
             ((s0[3][0] + s0[3][1]) + (s0[3][2] + s0[3][3]));                      \
    lrun1 += ((s1[0][0] + s1[0][1]) + (s1[0][2] + s1[0][3])) +                     \
             ((s1[1][0] + s1[1][1]) + (s1[1][2] + s1[1][3])) +                     \
             ((s1[2][0] + s1[2][1]) + (s1[2][2] + s1[2][3])) +                     \
             ((s1[3][0] + s1[3][1]) + (s1[3][2] + s1[3][3]));                      \
    /* P -> per-wave LDS, packed b64 writes (rows lr and 16+lr) */                 \
    _Pragma("unroll") for (int c = 0; c < 4; ++c) {                                \
      u32x2 w0, w1;                                                                \
      w0[0] = cvt_pk_bf16(s0[c][0], s0[c][1]);                                     \
      w0[1] = cvt_pk_bf16(s0[c][2], s0[c][3]);                                     \
      w1[0] = cvt_pk_bf16(s1[c][0], s1[c][1]);                                     \
      w1[1] = cvt_pk_bf16(s1[c][2], s1[c][3]);                                     \
      *(u32x2*)(Pb + lr * 128 + ((c * 32 + g * 8) ^ pswz)) = w0;                   \
      *(u32x2*)(Pb + (16 + lr) * 128 + ((c * 32 + g * 8) ^ pswz)) = w1;            \
    }                                                                              \
    /* PV both q-groups from shared vf regs */                                     \
    __builtin_amdgcn_s_setprio(1);                                                 \
    {                                                                              \
      s16x8 pb00 = *(const s16x8*)(Pb + lr * 128 + ((g * 16) ^ pswz));             \
      s16x8 pb01 = *(const s16x8*)(Pb + lr * 128 + ((64 + g * 16) ^ pswz));        \
      s16x8 pb10 = *(const s16x8*)(Pb + (16 + lr) * 128 + ((g * 16) ^ pswz));      \
      s16x8 pb11 =                                                                 \
          *(const s16x8*)(Pb + (16 + lr) * 128 + ((64 + g * 16) ^ pswz));          \
      _Pragma("unroll") for (int c = 0; c < 4; ++c) {                              \
        accO0[c] = mfma16(vf0[c], pb00, accO0[c]);                                 \
        accO0[c] = mfma16(vf1[c], pb01, accO0[c]);                                 \
        accO1[c] = mfma16(vf0[c], pb10, accO1[c]);                                 \
        accO1[c] = mfma16(vf1[c], pb11, accO1[c]);                                 \
      }                                                                            \
    }                                                                              \
    __builtin_amdgcn_s_setprio(0);                                                 \
  } while (0)

  // prologue: fill both buffers (8 loads in flight)
  STAGE(0, 0);
  STAGE(1, 64);

#pragma unroll 1
  for (int t = 0; t < 30; t += 2) {
    ASTEP(0, t, 4);
    ASTEP(1, t + 1, 4);
  }
  ASTEP(0, 30, 4);
  ASTEP(1, 31, 0);
#undef ASTEP
#undef STAGE

  // epilogue: reduce lrun across the 4 groups, then O^T[d][q] -> ctx[b,q,h,d]
  lrun0 += __shfl_xor(lrun0, 16);
  lrun0 += __shfl_xor(lrun0, 32);
  lrun1 += __shfl_xor(lrun1, 16);
  lrun1 += __shfl_xor(lrun1, 32);
  const float inv0 = 1.0f / lrun0;
  const float inv1 = 1.0f / lrun1;
  u16* op0 = ctx + ((size_t)(b * S_LEN + q0 + wid * 32 + lr)) * DM + h * HD;
  u16* op1 = op0 + (size_t)16 * DM;
#pragma unroll
  for (int c = 0; c < 4; ++c) {
    u32x2 w0, w1;
    w0[0] = cvt_pk_bf16(accO0[c][0] * inv0, accO0[c][1] * inv0);
    w0[1] = cvt_pk_bf16(accO0[c][2] * inv0, accO0[c][3] * inv0);
    w1[0] = cvt_pk_bf16(accO1[c][0] * inv1, accO1[c][1] * inv1);
    w1[1] = cvt_pk_bf16(accO1[c][2] * inv1, accO1[c][3] * inv1);
    *(u32x2*)(op0 + c * 16 + g * 4) = w0;
    *(u32x2*)(op1 + c * 16 + g * 4) = w1;
  }
}

// ---------------- launcher ----------------
extern "C" void kernel_launch(void* const* d_in, const int* in_sizes, int n_in,
                              void* d_out, int out_size, void* d_ws, size_t ws_size,
                              hipStream_t stream) {
  const float* Q = (const float*)d_in[0];
  const float* K = (const float*)d_in[1];
  const float* V = (const float*)d_in[2];
  const float* Wq = (const float*)d_in[3];
  const float* bq = (const float*)d_in[4];
  const float* Wk = (const float*)d_in[5];
  const float* bk = (const float*)d_in[6];
  const float* Wv = (const float*)d_in[7];
  const float* bv = (const float*)d_in[8];
  const float* Wo = (const float*)d_in[9];
  const float* bo = (const float*)d_in[10];
  float* out = (float*)d_out;

  char* ws = (char*)d_ws;
  const size_t SZ_T = (size_t)NB * S_LEN * DM * 2;  // 8.39 MB (bf16 tensor)
  const size_t SZ_W = (size_t)DM * DM * 2;          // 2.10 MB (bf16 weight)

  u16* Wqb = (u16*)(ws);
  u16* Wkb = (u16*)(ws + SZ_W);
  u16* Wvb = (u16*)(ws + 2 * SZ_W);
  u16* Wob = (u16*)(ws + 3 * SZ_W);
  u16* qb  = (u16*)(ws + 4 * SZ_W);
  u16* kb  = (u16*)(ws + 4 * SZ_W + SZ_T);
  u16* vtb = (u16*)(ws + 4 * SZ_W + 2 * SZ_T);
  u16* ctx = (u16*)(ws + 4 * SZ_W + 3 * SZ_T);  // total ~42 MB

  cvt_w_kernel<<<2048, 256, 0, stream>>>(Wq, Wk, Wv, Wo, Wqb, Wkb, Wvb, Wob);

  gemm_qkv_kernel<<<dim3(8, 32, 3), 256, 0, stream>>>(Q, K, V, Wqb, Wkb, Wvb,
                                                      bq, bk, bv, qb, kb, vtb);

  attn_kernel<<<512, 256, 0, stream>>>(qb, kb, vtb, ctx);

  gemm_out_kernel<<<dim3(8, 32), 256, 0, stream>>>(ctx, Wob, bo, out);
}